// Round 5
// baseline (51.487 us; speedup 1.0000x reference)
//
#include <hip/hip_runtime.h>
#include <hip/hip_fp16.h>

typedef unsigned int uint;

#define NUM 2048
#define SP 12
#define WIN 33
// f16-unit offsets into wbuf; all row strides keep 16B-aligned rows
#define S_WAE 0        // stride 40: floats 0..32 at local x
#define S_WAO 3960     // stride 40: floats 1..32 at local x-1
#define S_WBE 7920     // stride 24: floats 12..32 at local x-12
#define S_WBO 10296    // stride 24: floats 13..32 at local x-13
#define S_TOT 12672    // f16 units (25344 B)
#define HROW 28

union H2U { uint u; __half2 h2; };
__device__ __forceinline__ __half2 as_h2(uint u){ H2U p; p.u=u; return p.h2; }
__device__ __forceinline__ uint as_u(__half2 h){ H2U p; p.h2=h; return p.u; }

__global__ __launch_bounds__(128, 2) void simmap_kernel(
    const float* __restrict__ img, const float* __restrict__ img_sr,
    const float* __restrict__ sigma, const int* __restrict__ coords,
    float* __restrict__ out)
{
    __shared__ __align__(16) __half wbuf[S_TOT];
    __shared__ __align__(16) float hs[WIN*HROW];
    __shared__ __align__(16) uint part[50*13];

    const int n = blockIdx.x;
    const int imgid = blockIdx.y;
    const float* im = imgid ? img_sr : img;
    const int t = threadIdx.x;
    const int w = t >> 6;
    const int l = t & 63;
    const int r0 = coords[2*n];
    const int c0 = coords[2*n+1];

    // ---- zero the window copies (pads must be finite: NaN*0=NaN hazard) ----
    {
        uint4* z = (uint4*)wbuf;
        for (int f = t; f < S_TOT/8; f += 128) z[f] = uint4{0,0,0,0};
    }
    __syncthreads();

    // ---- stage f16 window, four shifted copies ----
    if (r0 >= 16 && r0 < 240 && c0 >= 16 && c0 < 240) {
        const float* base = im + (r0-16)*256 + (c0-16);
        for (int f = t; f < WIN*WIN; f += 128) {
            int r = f / WIN, x = f - r*WIN;
            int go = r*256 + x;
            #pragma unroll
            for (int c = 0; c < 3; ++c) {
                __half hv = __float2half(base[c*65536 + go]);
                int row = c*WIN + r;
                wbuf[S_WAE + row*40 + x] = hv;
                if (x >= 1)  wbuf[S_WAO + row*40 + x - 1]  = hv;
                if (x >= 12) wbuf[S_WBE + row*24 + x - 12] = hv;
                if (x >= 13) wbuf[S_WBO + row*24 + x - 13] = hv;
            }
        }
    } else {
        for (int f = t; f < WIN*WIN; f += 128) {
            int r = f / WIN, x = f - r*WIN;
            int ri = r0 + r - 16, ci = c0 + x - 16;
            bool inb = (ri >= 0 && ri < 256 && ci >= 0 && ci < 256);
            int go = ri*256 + ci;
            #pragma unroll
            for (int c = 0; c < 3; ++c) {
                float v = inb ? im[c*65536 + go] : 0.f;
                __half hv = __float2half(v);
                int row = c*WIN + r;
                wbuf[S_WAE + row*40 + x] = hv;
                if (x >= 1)  wbuf[S_WAO + row*40 + x - 1]  = hv;
                if (x >= 12) wbuf[S_WBE + row*24 + x - 12] = hv;
                if (x >= 13) wbuf[S_WBO + row*24 + x - 13] = hv;
            }
        }
    }
    __syncthreads();

    // ---- hs[r][d1] = sum_c sum_j w[c][r][d1+j]^2 (wave0, lanes<33, f32) ----
    if (w == 0 && l < WIN) {
        float sq3[33];
        #pragma unroll
        for (int x = 0; x < 33; ++x) sq3[x] = 0.f;
        #pragma unroll 1
        for (int c = 0; c < 3; ++c) {
            const uint* rp = (const uint*)&wbuf[S_WAE + (c*WIN + l)*40];
            uint U[17];
            #pragma unroll
            for (int q = 0; q < 4; ++q) {
                uint4 v = ((const uint4*)rp)[q];
                U[4*q+0]=v.x; U[4*q+1]=v.y; U[4*q+2]=v.z; U[4*q+3]=v.w;
            }
            U[16] = rp[16];
            #pragma unroll
            for (int k = 0; k < 17; ++k) {
                float2 f2 = __half22float2(as_h2(U[k]));
                sq3[2*k] += f2.x * f2.x;
                if (2*k + 1 < 33) sq3[2*k+1] += f2.y * f2.y;
            }
        }
        float s = 0.f;
        #pragma unroll
        for (int j = 0; j < 9; ++j) s += sq3[j];
        hs[l*HROW + 0] = s;
        #pragma unroll
        for (int d = 1; d < 25; ++d) { s += sq3[d+8] - sq3[d-1]; hs[l*HROW + d] = s; }
    }

    // ---- cross term via packed f16 fma ----
    const int half = l & 1;
    const int d0 = l >> 1;
    const int d0e = (l < 50) ? d0 : 0;
    const __half* pE = wbuf + (half ? S_WBE : S_WAE);
    const __half* pO = wbuf + (half ? S_WBO : S_WAO);
    const int str = half ? 24 : 40;

    __half2 acc[13];
    #pragma unroll
    for (int o = 0; o < 13; ++o) acc[o] = as_h2(0u);

    auto ROW = [&](int c, int i) {
        const int row = c*WIN + d0e + i;
        const uint4* e4 = (const uint4*)(pE + row*str);
        const uint4* o4 = (const uint4*)(pO + row*str);
        uint E[12], O[12];
        { uint4 v=e4[0]; E[0]=v.x;E[1]=v.y;E[2]=v.z;E[3]=v.w; }
        { uint4 v=e4[1]; E[4]=v.x;E[5]=v.y;E[6]=v.z;E[7]=v.w; }
        { uint4 v=e4[2]; E[8]=v.x;E[9]=v.y;E[10]=v.z;E[11]=v.w; }
        { uint4 v=o4[0]; O[0]=v.x;O[1]=v.y;O[2]=v.z;O[3]=v.w; }
        { uint4 v=o4[1]; O[4]=v.x;O[5]=v.y;O[6]=v.z;O[7]=v.w; }
        { uint4 v=o4[2]; O[8]=v.x;O[9]=v.y;O[10]=v.z;O[11]=v.w; }
        const uint* cq = (const uint*)(wbuf + S_WBE + (c*WIN + SP + i)*24);
        uint4 cv = *(const uint4*)cq;
        uint c4 = cq[4];
        __half2 cp0=as_h2(cv.x), cp1=as_h2(cv.y), cp2=as_h2(cv.z), cp3=as_h2(cv.w);
        __half2 cp8=as_h2(c4 & 0xFFFFu);   // (c[8], 0)
        #pragma unroll
        for (int o = 0; o < 13; ++o) {
            const uint* S = (o & 1) ? O : E;
            const int b = o >> 1;
            acc[o] = __hfma2(as_h2(S[b  ]), cp0, acc[o]);
            acc[o] = __hfma2(as_h2(S[b+1]), cp1, acc[o]);
            acc[o] = __hfma2(as_h2(S[b+2]), cp2, acc[o]);
            acc[o] = __hfma2(as_h2(S[b+3]), cp3, acc[o]);
            acc[o] = __hfma2(as_h2(S[b+4]), cp8, acc[o]);
        }
    };

    // wave0: c=0 i0..8 + c=2 i0..2 (12 rows, + hs + epilogue)
    // wave1: c=1 i0..8 + c=2 i3..8 (15 rows)
    {
        const int cA = w;
        #pragma unroll 2
        for (int i = 0; i < 9; ++i) ROW(cA, i);
        const int ib = w ? 3 : 0;
        const int ie = w ? 9 : 3;
        #pragma unroll 2
        for (int i = ib; i < ie; ++i) ROW(2, i);
    }

    if (w == 1 && l < 50) {
        #pragma unroll
        for (int o = 0; o < 13; ++o) part[l*13 + o] = as_u(acc[o]);
    }
    __syncthreads();
    if (w == 1 || l >= 50) return;

    // ---- epilogue (wave0, lanes<50) ----
    float cr[13];
    #pragma unroll
    for (int o = 0; o < 13; ++o) {
        __half2 s = __hadd2(acc[o], as_h2(part[l*13 + o]));
        float2 f2 = __half22float2(s);
        cr[o] = f2.x + f2.y;
    }

    const int d1b = half * 12;
    float cc = 0.f;
    #pragma unroll
    for (int i = 0; i < 9; ++i) cc += hs[(SP + i)*HROW + SP];

    float bs[13];
    #pragma unroll
    for (int o = 0; o < 13; ++o) bs[o] = 0.f;
    #pragma unroll
    for (int i = 0; i < 9; ++i) {
        const float* hr = &hs[(d0 + i)*HROW + d1b];
        float4 a = *(const float4*)hr;
        float4 b = *(const float4*)(hr + 4);
        float4 d2 = *(const float4*)(hr + 8);
        float hv[13] = {a.x,a.y,a.z,a.w,b.x,b.y,b.z,b.w,d2.x,d2.y,d2.z,d2.w,hr[12]};
        #pragma unroll
        for (int o = 0; o < 13; ++o) bs[o] += hv[o];
    }

    const float sg = fmaxf(sigma[0], 0.f);
    const float scl = -1.f / (243.f * sg);
    float* op = out + (size_t)(imgid*NUM + n)*625 + d0*25 + d1b;
    #pragma unroll
    for (int o = 0; o < 13; ++o)
        op[o] = __expf((bs[o] + cc - 2.f*cr[o]) * scl + 1e-20f);
}

extern "C" void kernel_launch(void* const* d_in, const int* in_sizes, int n_in,
                              void* d_out, int out_size, void* d_ws, size_t ws_size,
                              hipStream_t stream) {
    const float* img    = (const float*)d_in[0];
    const float* img_sr = (const float*)d_in[1];
    const float* sigma  = (const float*)d_in[2];
    const int*   coords = (const int*)d_in[3];
    float* out = (float*)d_out;
    dim3 grid(NUM, 2);
    simmap_kernel<<<grid, dim3(128), 0, stream>>>(img, img_sr, sigma, coords, out);
}

// Round 7
// 35.639 us; speedup vs baseline: 1.4447x; 1.4447x over previous
//
#include <hip/hip_runtime.h>
#include <hip/hip_fp16.h>

typedef unsigned int uint;
typedef __attribute__((ext_vector_type(2))) _Float16 half2_t;

#define NUM 2048
#define SP 12
#define WIN 33
#define RSTR 20                         // row stride, dwords (40 f16)
#define WA_DW (3*WIN*RSTR)              // 1980 dw: E pairs (s2m,s2m+1)
#define HS_STRIDE 14
#define HSE_DW (2*WA_DW)                // 3960
#define HSO_DW (HSE_DW + WIN*HS_STRIDE) // 4422
#define PART_DW (HSO_DW + WIN*HS_STRIDE)// 4884 ; part: 3*50*14 halves = 1050 dw
#define TOT_DW (PART_DW + 1050)         // 5934 dw = 23736 B

union U32H2 { uint u; half2_t h; };
__device__ __forceinline__ half2_t uh2(uint u){ U32H2 p; p.u=u; return p.h; }

#if __has_builtin(__builtin_amdgcn_fdot2)
__device__ __forceinline__ float fdot2(uint a, uint b, float c) {
    return __builtin_amdgcn_fdot2(uh2(a), uh2(b), c, false);
}
#else
__device__ __forceinline__ float fdot2(uint a, uint b, float c) {
    half2_t A = uh2(a), B = uh2(b);
    return fmaf((float)A.y, (float)B.y, fmaf((float)A.x, (float)B.x, c));
}
#endif

__global__ __launch_bounds__(256, 6) void simmap_kernel(
    const float* __restrict__ img, const float* __restrict__ img_sr,
    const float* __restrict__ sigma, const int* __restrict__ coords,
    float* __restrict__ out)
{
    __shared__ __align__(16) uint lds[TOT_DW];
    __half* wh = (__half*)lds;
    float*  lf = (float*)lds;

    const int n = blockIdx.x;
    const int imgid = blockIdx.y;
    const float* im = imgid ? img_sr : img;
    const int t = threadIdx.x;
    const int w = t >> 6;
    const int l = t & 63;
    const int r0 = coords[2*n];
    const int c0 = coords[2*n+1];

    // ---- stage f16 window: E copy (x at half-idx x) + O copy (x at x-1) ----
    if (r0 >= 16 && r0 < 240 && c0 >= 16 && c0 < 240) {
        const float* base = im + (r0-16)*256 + (c0-16);
        for (int f = t; f < WIN*WIN; f += 256) {
            int r = f / WIN, x = f - r*WIN;
            int go = r*256 + x;
            #pragma unroll
            for (int c = 0; c < 3; ++c) {
                __half hv = __float2half(base[c*65536 + go]);
                int rowh = (c*WIN + r)*40;
                wh[rowh + x] = hv;
                if (x >= 1)  wh[2*WA_DW + rowh + x - 1] = hv;
                if (x == 32) wh[rowh + 33] = __float2half(0.f); // zero s33 (E dw16.hi)
            }
        }
    } else {
        for (int f = t; f < WIN*WIN; f += 256) {
            int r = f / WIN, x = f - r*WIN;
            int ri = r0 + r - 16, ci = c0 + x - 16;
            bool inb = (ri >= 0 && ri < 256 && ci >= 0 && ci < 256);
            int go = ri*256 + ci;
            #pragma unroll
            for (int c = 0; c < 3; ++c) {
                float v = inb ? im[c*65536 + go] : 0.f;
                __half hv = __float2half(v);
                int rowh = (c*WIN + r)*40;
                wh[rowh + x] = hv;
                if (x >= 1)  wh[2*WA_DW + rowh + x - 1] = hv;
                if (x == 32) wh[rowh + 33] = __float2half(0.f);
            }
        }
    }
    __syncthreads();

    // ---- hs (wave0, lanes<33): parity-packed sliding sums of squares ----
    if (w == 0 && l < WIN) {
        float sq[33];
        #pragma unroll
        for (int x = 0; x < 33; ++x) sq[x] = 0.f;
        #pragma unroll 1
        for (int c = 0; c < 3; ++c) {
            const uint* rp = lds + (uint)(c*WIN + l)*RSTR;
            uint U[17];
            { uint4 v = *(const uint4*)(rp);    U[0]=v.x;U[1]=v.y;U[2]=v.z;U[3]=v.w; }
            { uint4 v = *(const uint4*)(rp+4);  U[4]=v.x;U[5]=v.y;U[6]=v.z;U[7]=v.w; }
            { uint4 v = *(const uint4*)(rp+8);  U[8]=v.x;U[9]=v.y;U[10]=v.z;U[11]=v.w; }
            { uint4 v = *(const uint4*)(rp+12); U[12]=v.x;U[13]=v.y;U[14]=v.z;U[15]=v.w; }
            U[16] = rp[16];
            #pragma unroll
            for (int k = 0; k < 17; ++k) {
                half2_t h = uh2(U[k]);
                float x0 = (float)h.x, x1 = (float)h.y;
                sq[2*k] += x0*x0;
                if (2*k + 1 < 33) sq[2*k+1] += x1*x1;
            }
        }
        float s = 0.f;
        #pragma unroll
        for (int j = 0; j < 9; ++j) s += sq[j];
        lf[HSE_DW + l*HS_STRIDE + 0] = s;
        #pragma unroll
        for (int d = 1; d < 25; ++d) {
            s += sq[d+8] - sq[d-1];
            if (d & 1) lf[HSO_DW + l*HS_STRIDE + (d>>1)] = s;
            else       lf[HSE_DW + l*HS_STRIDE + (d>>1)] = s;
        }
    }

    // ---- cross term: lane owns (d0=l>>1, parity=l&1); o = 2*oo+parity ----
    const int parity = l & 1;
    const int d0e = (l < 50) ? (l >> 1) : 0;
    const uint sbase = parity ? (uint)WA_DW : 0u;

    float acc[13];
    #pragma unroll
    for (int oo = 0; oo < 13; ++oo) acc[oo] = 0.f;

    // rows 0..26 split 4/7/8/8 across waves: 0-3 / 4-10 / 11-18 / 19-26
    const int base  = (w == 0) ? 0 : (w == 1) ? 4 : (w == 2) ? 11 : 19;
    const int nrows = (w == 0) ? 4 : (w == 1) ? 7 : 8;

    #pragma unroll 1
    for (int ridx = base; ridx < base + nrows; ++ridx) {
        const int c = ridx / 9;
        const int i = ridx - 9*c;
        const uint* sp = lds + sbase + (uint)(c*WIN + d0e + i)*RSTR;
        uint S[17];
        { uint4 v = *(const uint4*)(sp);    S[0]=v.x;S[1]=v.y;S[2]=v.z;S[3]=v.w; }
        { uint4 v = *(const uint4*)(sp+4);  S[4]=v.x;S[5]=v.y;S[6]=v.z;S[7]=v.w; }
        { uint4 v = *(const uint4*)(sp+8);  S[8]=v.x;S[9]=v.y;S[10]=v.z;S[11]=v.w; }
        { uint4 v = *(const uint4*)(sp+12); S[12]=v.x;S[13]=v.y;S[14]=v.z;S[15]=v.w; }
        S[16] = sp[16];
        const uint* cp = lds + (uint)(c*WIN + SP + i)*RSTR;   // center row (broadcast)
        uint cw[5];
        { uint2 v = *(const uint2*)(cp+6); cw[0]=v.x; cw[1]=v.y; }
        { uint2 v = *(const uint2*)(cp+8); cw[2]=v.x; cw[3]=v.y; }
        cw[4] = cp[10] & 0xFFFFu;                              // (c8, 0)
        #pragma unroll
        for (int oo = 0; oo < 13; ++oo) {
            float a = acc[oo];
            #pragma unroll
            for (int jj = 0; jj < 5; ++jj)
                a = fdot2(S[oo + jj], cw[jj], a);
            acc[oo] = a;
        }
    }

    if (w != 0 && l < 50) {
        #pragma unroll
        for (int oo = 0; oo < 13; ++oo)
            wh[2*PART_DW + (w-1)*700 + l*14 + oo] = __float2half(acc[oo]);
    }
    __syncthreads();
    if (w != 0 || l >= 50) return;

    // ---- epilogue (wave0, lanes<50) ----
    float cr[13];
    #pragma unroll
    for (int oo = 0; oo < 13; ++oo) {
        float s = acc[oo];
        #pragma unroll
        for (int ww = 0; ww < 3; ++ww)
            s += __half2float(wh[2*PART_DW + ww*700 + l*14 + oo]);
        cr[oo] = s;
    }

    const int d0 = l >> 1;
    const int hsb = parity ? HSO_DW : HSE_DW;
    float bs[13];
    #pragma unroll
    for (int oo = 0; oo < 13; ++oo) bs[oo] = 0.f;
    #pragma unroll
    for (int i = 0; i < 9; ++i) {
        const float* hr = lf + hsb + (d0 + i)*HS_STRIDE;
        float2 a = *(const float2*)(hr);
        float2 b = *(const float2*)(hr + 2);
        float2 c2 = *(const float2*)(hr + 4);
        float2 d2 = *(const float2*)(hr + 6);
        float2 e2 = *(const float2*)(hr + 8);
        float2 f2 = *(const float2*)(hr + 10);
        bs[0]+=a.x; bs[1]+=a.y; bs[2]+=b.x; bs[3]+=b.y;
        bs[4]+=c2.x; bs[5]+=c2.y; bs[6]+=d2.x; bs[7]+=d2.y;
        bs[8]+=e2.x; bs[9]+=e2.y; bs[10]+=f2.x; bs[11]+=f2.y;
        bs[12]+=hr[12];
    }
    float cc = 0.f;
    #pragma unroll
    for (int i = 0; i < 9; ++i) cc += lf[HSE_DW + (SP + i)*HS_STRIDE + 6];

    const float sg = fmaxf(sigma[0], 0.f);
    const float scl = -1.f / (243.f * sg);
    float* op = out + (size_t)(imgid*NUM + n)*625 + d0*25 + parity;
    #pragma unroll
    for (int oo = 0; oo < 13; ++oo) {
        if (parity && oo == 12) break;      // odd half has 12 outputs
        op[2*oo] = __expf((bs[oo] + cc - 2.f*cr[oo]) * scl + 1e-20f);
    }
}

extern "C" void kernel_launch(void* const* d_in, const int* in_sizes, int n_in,
                              void* d_out, int out_size, void* d_ws, size_t ws_size,
                              hipStream_t stream) {
    const float* img    = (const float*)d_in[0];
    const float* img_sr = (const float*)d_in[1];
    const float* sigma  = (const float*)d_in[2];
    const int*   coords = (const int*)d_in[3];
    float* out = (float*)d_out;
    dim3 grid(NUM, 2);
    simmap_kernel<<<grid, dim3(256), 0, stream>>>(img, img_sr, sigma, coords, out);
}